// Round 11
// baseline (201.172 us; speedup 1.0000x reference)
//
#include <hip/hip_runtime.h>
#include <hip/hip_bf16.h>
#include <stdint.h>

typedef __attribute__((ext_vector_type(8))) short    bf16x8;  // 8×16-bit = 4 VGPR (MFMA A/B frag)
typedef __attribute__((ext_vector_type(8))) _Float16 f16x8;
typedef __attribute__((ext_vector_type(4))) float    f32x4;   // MFMA acc

typedef __attribute__((address_space(1))) void GV;            // global
typedef __attribute__((address_space(3))) void LV;            // LDS

__device__ __forceinline__ unsigned short f2bf(float f){
  union { float f; unsigned u; } x; x.f = f;
  unsigned r = x.u + 0x7fffu + ((x.u >> 16) & 1u);            // RNE
  return (unsigned short)(r >> 16);
}
__device__ __forceinline__ float bf2f(unsigned short h){
  union { unsigned u; float f; } x; x.u = ((unsigned)h) << 16; return x.f;
}
__device__ __forceinline__ unsigned short f2h(float f){
  union { _Float16 h; unsigned short u; } c; c.h = (_Float16)f; return c.u;  // RNE
}

template<bool F16>
__device__ __forceinline__ void mma16(f32x4& acc, bf16x8 a, bf16x8 b){
  if constexpr (F16)
    acc = __builtin_amdgcn_mfma_f32_16x16x32_f16(__builtin_bit_cast(f16x8, a),
                                                 __builtin_bit_cast(f16x8, b), acc, 0, 0, 0);
  else
    acc = __builtin_amdgcn_mfma_f32_16x16x32_bf16(a, b, acc, 0, 0, 0);
}

// r8-verified barrier/wait forms (lockstep schedule is the measured best of 4 variants)
#define SBAR()  __builtin_amdgcn_s_barrier()
#define LGKM0() asm volatile("s_waitcnt lgkmcnt(0)" ::: "memory")

// swizzled LDS frag read (128B rows, byte ^= (row&7)<<4) — used by k_projQK
__device__ __forceinline__ bf16x8 frag_ld(const unsigned short* lds, int r, int k){
  int byte = ((r << 7) + (k << 1)) ^ ((r & 7) << 4);
  return *(const bf16x8*)((const char*)lds + byte);
}

__device__ __forceinline__ void stage_tile(const unsigned short* __restrict__ src, int ld,
                                           unsigned short* lds, int tid){
  #pragma unroll
  for (int t = 0; t < 4; ++t){
    int idx = t*256 + tid;
    int row = idx >> 3;
    int kc  = (idx & 7) ^ (row & 7);
    const unsigned short* g = src + (size_t)row*ld + kc*8;
    __builtin_amdgcn_global_load_lds((GV*)g, (LV*)(lds + idx*8), 16, 0, 0);
  }
}

#define ZERO_ACC4(acc) { _Pragma("unroll") for (int i_=0;i_<4;++i_) _Pragma("unroll") for (int j_=0;j_<4;++j_) acc[i_][j_] = (f32x4){0.f,0.f,0.f,0.f}; }
#define ZERO_ACC8(acc) { _Pragma("unroll") for (int i_=0;i_<8;++i_) _Pragma("unroll") for (int j_=0;j_<4;++j_) acc[i_][j_] = (f32x4){0.f,0.f,0.f,0.f}; }

// ============== 256² 4-phase core (r8 lockstep schedule — verified) ==============
// LDS (128KB): Abuf0 @0, Abuf1 @32KB, Bbuf0 @64KB, Bbuf1 @96KB.
// Row-major [256][64] 16-bit tiles, swizzle byte ^= (row&7)<<4 (pre-swizzled global
// source + swizzled ds_read addr; linear LDS dest — rule #21). kk offsets INSIDE
// the XOR; only row-multiple offsets (BUF*32768, mf*2048) are additive.
__device__ __forceinline__ void stg2(const unsigned short* g, size_t qq, unsigned short* d){
  __builtin_amdgcn_global_load_lds((GV*)g, (LV*)d, 16, 0, 0);
  __builtin_amdgcn_global_load_lds((GV*)(g + qq), (LV*)(d + 4096), 16, 0, 0);
}

template<bool F16, int BUF>
__device__ __forceinline__ void ktile256(int t, int nkt,
    const unsigned short*& gA0, const unsigned short*& gA1,
    const unsigned short*& gB0, const unsigned short*& gB1,
    size_t qA, size_t qB,
    unsigned short* dA, unsigned short* dB,
    const char* lA_k0, const char* lA_k1, const char* lB_k0, const char* lB_k1,
    f32x4 (&acc)[8][4]){
  bf16x8 af[4], bfr[4];

  // ---- P1: A kk0 mf0-3 + B kk0; stage A(t+1) h0 -> other buf
  #pragma unroll
  for (int i = 0; i < 4; ++i) af[i]  = *(const bf16x8*)(lA_k0 + BUF*32768 + i*2048);
  #pragma unroll
  for (int i = 0; i < 4; ++i) bfr[i] = *(const bf16x8*)(lB_k0 + BUF*32768 + i*2048);
  if (t + 1 < nkt) stg2(gA0 + 64, qA, dA + (BUF^1)*16384);
  SBAR(); LGKM0();
  __builtin_amdgcn_s_setprio(1);
  #pragma unroll
  for (int mf = 0; mf < 4; ++mf)
    #pragma unroll
    for (int nf = 0; nf < 4; ++nf) mma16<F16>(acc[mf][nf], af[mf], bfr[nf]);
  __builtin_amdgcn_s_setprio(0);
  SBAR();

  // ---- P2: A kk0 mf4-7 (reuse B); stage A(t+1) h1
  #pragma unroll
  for (int i = 0; i < 4; ++i) af[i] = *(const bf16x8*)(lA_k0 + BUF*32768 + (4+i)*2048);
  if (t + 1 < nkt) stg2(gA1 + 64, qA, dA + (BUF^1)*16384 + 8192);
  SBAR(); LGKM0();
  __builtin_amdgcn_s_setprio(1);
  #pragma unroll
  for (int mf = 0; mf < 4; ++mf)
    #pragma unroll
    for (int nf = 0; nf < 4; ++nf) mma16<F16>(acc[mf+4][nf], af[mf], bfr[nf]);
  __builtin_amdgcn_s_setprio(0);
  SBAR();

  // ---- P3: A kk1 mf0-3 + B kk1; stage B(t+2) h0 (half-tile granularity)
  #pragma unroll
  for (int i = 0; i < 4; ++i) af[i]  = *(const bf16x8*)(lA_k1 + BUF*32768 + i*2048);
  #pragma unroll
  for (int i = 0; i < 4; ++i) bfr[i] = *(const bf16x8*)(lB_k1 + BUF*32768 + i*2048);
  if (t + 2 < nkt) stg2(gB0 + 128, qB, dB + BUF*16384);
  SBAR(); LGKM0();
  __builtin_amdgcn_s_setprio(1);
  #pragma unroll
  for (int mf = 0; mf < 4; ++mf)
    #pragma unroll
    for (int nf = 0; nf < 4; ++nf) mma16<F16>(acc[mf][nf], af[mf], bfr[nf]);
  __builtin_amdgcn_s_setprio(0);
  SBAR();

  // ---- P4: A kk1 mf4-7; stage B(t+2) h1; counted vmcnt (leave B(t+2)'s 4 in flight)
  #pragma unroll
  for (int i = 0; i < 4; ++i) af[i] = *(const bf16x8*)(lA_k1 + BUF*32768 + (4+i)*2048);
  if (t + 2 < nkt){
    stg2(gB1 + 128, qB, dB + BUF*16384 + 8192);
    asm volatile("s_waitcnt vmcnt(4)" ::: "memory");   // tile t+1 landed; B(t+2) in flight
  } else if (t + 1 < nkt){
    asm volatile("s_waitcnt vmcnt(0)" ::: "memory");   // tail: drain A(t+1) (+ any prologue leftovers)
  }
  SBAR(); LGKM0();
  __builtin_amdgcn_s_setprio(1);
  #pragma unroll
  for (int mf = 0; mf < 4; ++mf)
    #pragma unroll
    for (int nf = 0; nf < 4; ++nf) mma16<F16>(acc[mf+4][nf], af[mf], bfr[nf]);
  __builtin_amdgcn_s_setprio(0);
  SBAR();

  gA0 += 64; gA1 += 64; gB0 += 64; gB1 += 64;          // advance to next K-tile
}

template<bool F16>
__device__ __forceinline__ void gemm256(const unsigned short* __restrict__ Ab, int lda,
                                        const unsigned short* __restrict__ Bb, int ldb,
                                        int nkt, unsigned short* sm, f32x4 (&acc)[8][4]){
  const int tid  = threadIdx.x;
  const int lane = tid & 63, l15 = lane & 15, lg = lane >> 4;
  const int wid  = tid >> 6;
  const int wrow0 = (wid >> 2) << 7;     // 0 / 128
  const int wcol0 = (wid & 3) << 6;      // 0 / 64 / 128 / 192

  const int srow = tid >> 3;                          // 0..63
  const int scol = ((tid & 7) ^ (srow & 7)) << 3;     // pre-swizzled chunk
  const unsigned short* gA0 = Ab + (size_t)srow*lda + scol;
  const unsigned short* gA1 = gA0 + (size_t)128*lda;
  const unsigned short* gB0 = Bb + (size_t)srow*ldb + scol;
  const unsigned short* gB1 = gB0 + (size_t)128*ldb;
  const size_t qA = (size_t)64*lda, qB = (size_t)64*ldb;
  unsigned short* dA = sm + tid*8;                    // linear LDS dests
  unsigned short* dB = sm + 32768 + tid*8;

  const int mswz = (l15 & 7) << 4;
  const char* smc = (const char*)sm;
  const char* lA_k0 = smc + ((wrow0 + l15) << 7) + (((lg << 4))      ^ mswz);
  const char* lA_k1 = smc + ((wrow0 + l15) << 7) + ((64 + (lg << 4)) ^ mswz);
  const char* lB_k0 = smc + 65536 + ((wcol0 + l15) << 7) + (((lg << 4))      ^ mswz);
  const char* lB_k1 = smc + 65536 + ((wcol0 + l15) << 7) + ((64 + (lg << 4)) ^ mswz);

  // prologue: A(0) h0+h1 -> Abuf0, B(0) -> Bbuf0, B(1) -> Bbuf1
  stg2(gA0, qA, dA);          stg2(gA1, qA, dA + 8192);
  stg2(gB0, qB, dB);          stg2(gB1, qB, dB + 8192);
  stg2(gB0 + 64, qB, dB + 16384);
  stg2(gB1 + 64, qB, dB + 16384 + 8192);
  asm volatile("s_waitcnt vmcnt(4)" ::: "memory");    // tile 0 fully landed
  SBAR();

  for (int t = 0; t < nkt; t += 2){
    ktile256<F16,0>(t,   nkt, gA0,gA1,gB0,gB1,qA,qB,dA,dB,lA_k0,lA_k1,lB_k0,lB_k1,acc);
    ktile256<F16,1>(t+1, nkt, gA0,gA1,gB0,gB1,qA,qB,dA,dB,lA_k0,lA_k1,lB_k0,lB_k1,acc);
  }
}

// ================= W transpose+convert (kept: tiny, scattered reads once) =================
__global__ __launch_bounds__(256) void k_cvt_wt(const float* __restrict__ Wq, const float* __restrict__ Wk,
                                                const float* __restrict__ Wv, unsigned short* __restrict__ Wt){
  int n = blockIdx.x*32 + threadIdx.x;
  int k = blockIdx.y*8  + threadIdx.y;
  float v;
  if (n < 128)      v = Wq[(size_t)k*128  + n];
  else if (n < 256) v = Wk[(size_t)k*128  + (n-128)];
  else              v = Wv[(size_t)k*1024 + (n-256)];
  Wt[(size_t)n*1024 + k] = f2h(v);
}

// ================= Q/K projection + FUSED x->fp16 convert (verified round 10) =================
__global__ __launch_bounds__(256) void k_projQK(const float* __restrict__ x,
                                                const unsigned short* __restrict__ Wt,
                                                const float* __restrict__ bq, const float* __restrict__ bk,
                                                unsigned short* __restrict__ Qh, unsigned short* __restrict__ Kh,
                                                unsigned short* __restrict__ xh){
  __shared__ unsigned short lsA[128*64], lsB[128*64];
  const int m0  = blockIdx.x * 128;
  const int sel = blockIdx.y;                // 0 = Q, 1 = K
  const int tid = threadIdx.x, lane = tid & 63;
  const int wr = ((tid >> 7) & 1) << 6;
  const int wc = ((tid >> 6) & 1) << 6;
  const int l15 = lane & 15, lg = lane >> 4;

  f32x4 acc[4][4]; ZERO_ACC4(acc);

  for (int kt = 0; kt < 16; ++kt){
    stage_tile(Wt + (size_t)sel*128*1024 + (size_t)kt*64, 1024, lsB, tid);
    #pragma unroll
    for (int t = 0; t < 4; ++t){
      int idx = t*256 + tid;
      int row = idx >> 3;
      int kc  = (idx & 7) ^ (row & 7);
      const float* gx = x + (size_t)(m0 + row)*1024 + kt*64 + kc*8;
      float4 v0 = *(const float4*)gx;
      float4 v1 = *(const float4*)(gx + 4);
      bf16x8 pk;
      pk[0] = (short)f2h(v0.x); pk[1] = (short)f2h(v0.y);
      pk[2] = (short)f2h(v0.z); pk[3] = (short)f2h(v0.w);
      pk[4] = (short)f2h(v1.x); pk[5] = (short)f2h(v1.y);
      pk[6] = (short)f2h(v1.z); pk[7] = (short)f2h(v1.w);
      *(bf16x8*)(lsA + idx*8) = pk;
      if (sel == 0) *(bf16x8*)(xh + (size_t)(m0 + row)*1024 + kt*64 + kc*8) = pk;
    }
    __syncthreads();
    #pragma unroll
    for (int kk = 0; kk < 2; ++kk){
      bf16x8 af[4], bfr[4];
      #pragma unroll
      for (int mf = 0; mf < 4; ++mf) af[mf]  = frag_ld(lsA, wr + mf*16 + l15, kk*32 + lg*8);
      #pragma unroll
      for (int nf = 0; nf < 4; ++nf) bfr[nf] = frag_ld(lsB, wc + nf*16 + l15, kk*32 + lg*8);
      #pragma unroll
      for (int mf = 0; mf < 4; ++mf)
        #pragma unroll
        for (int nf = 0; nf < 4; ++nf)
          mma16<true>(acc[mf][nf], af[mf], bfr[nf]);
    }
    __syncthreads();
  }

  unsigned short* T  = sel ? Kh : Qh;
  const float* bias  = sel ? bk : bq;
  #pragma unroll
  for (int mf = 0; mf < 4; ++mf){
    #pragma unroll
    for (int nf = 0; nf < 4; ++nf){
      int c = wc + nf*16 + l15;
      float bi = bias[c];
      #pragma unroll
      for (int r = 0; r < 4; ++r){
        int gr = m0 + wr + mf*16 + lg*4 + r;
        T[(size_t)gr*128 + c] = f2h(acc[mf][nf][r] + bi);
      }
    }
  }
}

// ================= V projection: 256² core, grid 64M x 4N = 256 blocks (one pass) =================
__global__ __launch_bounds__(512, 2) void k_projV(const unsigned short* __restrict__ xh,
                                                  const unsigned short* __restrict__ Wt,
                                                  const float* __restrict__ bv,
                                                  unsigned short* __restrict__ Vt){
  extern __shared__ unsigned short sm[];
  const int bid = blockIdx.x;
  const int m0 = (bid & 63) << 8;            // 0..16128
  const int n0 = (bid >> 6) << 8;            // 0..768 (V column block)

  f32x4 acc[8][4]; ZERO_ACC8(acc);
  gemm256<true>(xh + (size_t)m0*1024, 1024,
                Wt + (size_t)(256 + n0)*1024, 1024, 16, sm, acc);

  const int tid = threadIdx.x, lane = tid & 63, l15 = lane & 15, lg = lane >> 4;
  const int wid = tid >> 6;
  const int wrow0 = (wid >> 2) << 7;
  const int wcol0 = (wid & 3) << 6;

  #pragma unroll
  for (int mf = 0; mf < 8; ++mf){
    int gr0 = m0 + wrow0 + mf*16 + lg*4;     // 4 consecutive seq rows
    int b = gr0 >> 11, t0 = gr0 & 2047;
    #pragma unroll
    for (int nf = 0; nf < 4; ++nf){
      int j = n0 + wcol0 + nf*16 + l15;      // 0..1023
      float bi = bv[j];
      ushort4 pk;
      pk.x = f2bf(acc[mf][nf][0] + bi);
      pk.y = f2bf(acc[mf][nf][1] + bi);
      pk.z = f2bf(acc[mf][nf][2] + bi);
      pk.w = f2bf(acc[mf][nf][3] + bi);
      *(ushort4*)(Vt + ((size_t)b*1024 + j)*2048 + t0) = pk;
    }
  }
}

// ================= scores: 256² core, grid 512 (2 clean passes), exp epilogue =================
// NEW this round: replaces the 128² 2-phase scores kernel. b = bid&7 -> XCD-local
// Q/K panels. nkt=2 (K=128) exercises the core's verified prologue/tail paths:
// A(1) staged in P1/P2 of t=0; drained (with prologue's B(1)) by the t+1<nkt
// vmcnt(0) in P4 before t=1 reads buf1. MFMA K-order (0,32,64,96) identical to
// the old core -> P bit-identical; lsum atomic order nondeterministic as before.
__global__ __launch_bounds__(512, 2) void k_scores2(const unsigned short* __restrict__ Qh,
                                                    const unsigned short* __restrict__ Kh,
                                                    unsigned short* __restrict__ P,
                                                    float* __restrict__ lsum){
  extern __shared__ unsigned short sm[];
  const int bid = blockIdx.x;
  const int b   = bid & 7;
  const int r2  = bid >> 3;                  // 0..63
  const int s0  = (r2 >> 3) << 8;            // 0..1792
  const int t0  = (r2 & 7) << 8;

  f32x4 acc[8][4]; ZERO_ACC8(acc);
  gemm256<true>(Qh + ((size_t)b*2048 + s0)*128, 128,
                Kh + ((size_t)b*2048 + t0)*128, 128, 2, sm, acc);

  const int tid = threadIdx.x, lane = tid & 63, l15 = lane & 15, lg = lane >> 4;
  const int wid = tid >> 6;
  const int wrow0 = (wid >> 2) << 7;
  const int wcol0 = (wid & 3) << 6;

  unsigned short* Pb = P + (size_t)b*2048*2048;
  float* lb = lsum + b*2048;

  #pragma unroll
  for (int mf = 0; mf < 8; ++mf){
    #pragma unroll
    for (int r = 0; r < 4; ++r){
      int sr = s0 + wrow0 + mf*16 + lg*4 + r;
      float rsum = 0.f;
      #pragma unroll
      for (int nf = 0; nf < 4; ++nf){
        float e = __expf(acc[mf][nf][r]);
        unsigned short h = f2bf(e);
        int tc = t0 + wcol0 + nf*16 + l15;
        Pb[(size_t)sr*2048 + tc] = h;
        rsum += bf2f(h);                     // sum the ROUNDED values
      }
      #pragma unroll
      for (int d = 1; d < 16; d <<= 1) rsum += __shfl_xor(rsum, d);
      if (l15 == 0) atomicAdd(&lb[sr], rsum);
    }
  }
}

// ================= PV: 256² core, grid 256 (batch = bid&7 -> XCD) =================
__global__ __launch_bounds__(512, 2) void k_pv8(const unsigned short* __restrict__ P,
                                                const unsigned short* __restrict__ Vt,
                                                const float* __restrict__ lsum,
                                                float* __restrict__ out){
  extern __shared__ unsigned short sm[];
  const int bid = blockIdx.x;
  const int b   = bid & 7;
  const int r2  = bid >> 3;
  const int s0  = (r2 >> 2) << 8;
  const int j0  = (r2 & 3) << 8;

  f32x4 acc[8][4]; ZERO_ACC8(acc);
  gemm256<false>(P  + ((size_t)b*2048 + s0)*2048, 2048,
                 Vt + ((size_t)b*1024 + j0)*2048, 2048, 32, sm, acc);

  const int tid = threadIdx.x, lane = tid & 63, l15 = lane & 15, lg = lane >> 4;
  const int wid = tid >> 6;
  const int wrow0 = (wid >> 2) << 7;
  const int wcol0 = (wid & 3) << 6;

  const float* lb = lsum + b*2048;
  float* ob = out + (size_t)b*2048*1024;
  #pragma unroll
  for (int mf = 0; mf < 8; ++mf){
    #pragma unroll
    for (int r = 0; r < 4; ++r){
      int sr = s0 + wrow0 + mf*16 + lg*4 + r;
      float rl = 1.0f / lb[sr];
      #pragma unroll
      for (int nf = 0; nf < 4; ++nf){
        int jc = j0 + wcol0 + nf*16 + l15;
        float v = acc[mf][nf][r] * rl;
        ob[(size_t)sr*1024 + jc] = 1.0f - 2.0f/(1.0f + __expf(2.0f*v));
      }
    }
  }
}

extern "C" void kernel_launch(void* const* d_in, const int* in_sizes, int n_in,
                              void* d_out, int out_size, void* d_ws, size_t ws_size,
                              hipStream_t stream){
  const float* x  = (const float*)d_in[0];
  const float* Wq = (const float*)d_in[1];
  const float* bq = (const float*)d_in[2];
  const float* Wk = (const float*)d_in[3];
  const float* bk = (const float*)d_in[4];
  const float* Wv = (const float*)d_in[5];
  const float* bv = (const float*)d_in[6];
  float* out = (float*)d_out;

  char* ws = (char*)d_ws;
  const size_t MB = 1024*1024;
  unsigned short* Wt   = (unsigned short*)(ws);            // [1280][1024] fp16
  unsigned short* Qh   = (unsigned short*)(ws + 4*MB);     // [16384][128] fp16
  unsigned short* Kh   = (unsigned short*)(ws + 8*MB);
  unsigned short* Vt   = (unsigned short*)(ws + 12*MB);    // [8][1024][2048] bf16
  unsigned short* P    = (unsigned short*)(ws + 44*MB);    // [8][2048][2048] bf16
  float*          lsum = (float*)(ws + 108*MB);            // [8][2048] f32
  unsigned short* xh   = (unsigned short*)d_out;           // scratch: x fp16 in out buf (written by k_projQK sel0)

  hipMemsetAsync(lsum, 0, 16384*sizeof(float), stream);
  k_cvt_wt <<<dim3(40,128), dim3(32,8), 0, stream>>>(Wq, Wk, Wv, Wt);
  k_projQK <<<dim3(128,2), 256, 0, stream>>>(x, Wt, bq, bk, Qh, Kh, xh);
  k_projV  <<<256, 512, 131072, stream>>>(xh, Wt, bv, Vt);
  k_scores2<<<512, 512, 131072, stream>>>(Qh, Kh, P, lsum);
  k_pv8    <<<256, 512, 131072, stream>>>(P, Vt, lsum, out);
}

// Round 12
// 192.039 us; speedup vs baseline: 1.0476x; 1.0476x over previous
//
#include <hip/hip_runtime.h>
#include <hip/hip_bf16.h>
#include <stdint.h>

typedef __attribute__((ext_vector_type(8))) short    bf16x8;  // 8×16-bit = 4 VGPR (MFMA A/B frag)
typedef __attribute__((ext_vector_type(8))) _Float16 f16x8;
typedef __attribute__((ext_vector_type(4))) float    f32x4;   // MFMA acc

typedef __attribute__((address_space(1))) void GV;            // global
typedef __attribute__((address_space(3))) void LV;            // LDS

__device__ __forceinline__ unsigned short f2bf(float f){
  union { float f; unsigned u; } x; x.f = f;
  unsigned r = x.u + 0x7fffu + ((x.u >> 16) & 1u);            // RNE
  return (unsigned short)(r >> 16);
}
__device__ __forceinline__ float bf2f(unsigned short h){
  union { unsigned u; float f; } x; x.u = ((unsigned)h) << 16; return x.f;
}
__device__ __forceinline__ unsigned short f2h(float f){
  union { _Float16 h; unsigned short u; } c; c.h = (_Float16)f; return c.u;  // RNE
}

template<bool F16>
__device__ __forceinline__ void mma16(f32x4& acc, bf16x8 a, bf16x8 b){
  if constexpr (F16)
    acc = __builtin_amdgcn_mfma_f32_16x16x32_f16(__builtin_bit_cast(f16x8, a),
                                                 __builtin_bit_cast(f16x8, b), acc, 0, 0, 0);
  else
    acc = __builtin_amdgcn_mfma_f32_16x16x32_bf16(a, b, acc, 0, 0, 0);
}

// r8-verified barrier/wait forms (lockstep schedule is the measured best of 4 variants)
#define SBAR()  __builtin_amdgcn_s_barrier()
#define LGKM0() asm volatile("s_waitcnt lgkmcnt(0)" ::: "memory")

// swizzled LDS frag read (128B rows, byte ^= (row&7)<<4)
__device__ __forceinline__ bf16x8 frag_ld(const unsigned short* lds, int r, int k){
  int byte = ((r << 7) + (k << 1)) ^ ((r & 7) << 4);
  return *(const bf16x8*)((const char*)lds + byte);
}

__device__ __forceinline__ void stage_tile(const unsigned short* __restrict__ src, int ld,
                                           unsigned short* lds, int tid){
  #pragma unroll
  for (int t = 0; t < 4; ++t){
    int idx = t*256 + tid;
    int row = idx >> 3;
    int kc  = (idx & 7) ^ (row & 7);
    const unsigned short* g = src + (size_t)row*ld + kc*8;
    __builtin_amdgcn_global_load_lds((GV*)g, (LV*)(lds + idx*8), 16, 0, 0);
  }
}

template<bool F16>
__device__ __forceinline__ void gemm_core(const unsigned short* __restrict__ At,
                                          const unsigned short* __restrict__ Bt,
                                          int lda, int ldb, int nkt,
                                          unsigned short* lsA, unsigned short* lsB,
                                          f32x4 (&acc)[4][4]){
  const int tid  = threadIdx.x;
  const int lane = tid & 63;
  const int wr = ((tid >> 7) & 1) << 6;
  const int wc = ((tid >> 6) & 1) << 6;
  const int l15 = lane & 15, lg = lane >> 4;

  for (int kt = 0; kt < nkt; ++kt){
    stage_tile(At + (size_t)kt*64, lda, lsA, tid);
    stage_tile(Bt + (size_t)kt*64, ldb, lsB, tid);
    __syncthreads();
    #pragma unroll
    for (int kk = 0; kk < 2; ++kk){
      bf16x8 af[4], bfr[4];
      #pragma unroll
      for (int mf = 0; mf < 4; ++mf) af[mf]  = frag_ld(lsA, wr + mf*16 + l15, kk*32 + lg*8);
      #pragma unroll
      for (int nf = 0; nf < 4; ++nf) bfr[nf] = frag_ld(lsB, wc + nf*16 + l15, kk*32 + lg*8);
      #pragma unroll
      for (int mf = 0; mf < 4; ++mf)
        #pragma unroll
        for (int nf = 0; nf < 4; ++nf)
          mma16<F16>(acc[mf][nf], af[mf], bfr[nf]);
    }
    __syncthreads();
  }
}

#define ZERO_ACC4(acc) { _Pragma("unroll") for (int i_=0;i_<4;++i_) _Pragma("unroll") for (int j_=0;j_<4;++j_) acc[i_][j_] = (f32x4){0.f,0.f,0.f,0.f}; }
#define ZERO_ACC8(acc) { _Pragma("unroll") for (int i_=0;i_<8;++i_) _Pragma("unroll") for (int j_=0;j_<4;++j_) acc[i_][j_] = (f32x4){0.f,0.f,0.f,0.f}; }

// ============== 256² 4-phase core (r8 lockstep schedule — verified) ==============
__device__ __forceinline__ void stg2(const unsigned short* g, size_t qq, unsigned short* d){
  __builtin_amdgcn_global_load_lds((GV*)g, (LV*)d, 16, 0, 0);
  __builtin_amdgcn_global_load_lds((GV*)(g + qq), (LV*)(d + 4096), 16, 0, 0);
}

template<bool F16, int BUF>
__device__ __forceinline__ void ktile256(int t, int nkt,
    const unsigned short*& gA0, const unsigned short*& gA1,
    const unsigned short*& gB0, const unsigned short*& gB1,
    size_t qA, size_t qB,
    unsigned short* dA, unsigned short* dB,
    const char* lA_k0, const char* lA_k1, const char* lB_k0, const char* lB_k1,
    f32x4 (&acc)[8][4]){
  bf16x8 af[4], bfr[4];

  // ---- P1: A kk0 mf0-3 + B kk0; stage A(t+1) h0 -> other buf
  #pragma unroll
  for (int i = 0; i < 4; ++i) af[i]  = *(const bf16x8*)(lA_k0 + BUF*32768 + i*2048);
  #pragma unroll
  for (int i = 0; i < 4; ++i) bfr[i] = *(const bf16x8*)(lB_k0 + BUF*32768 + i*2048);
  if (t + 1 < nkt) stg2(gA0 + 64, qA, dA + (BUF^1)*16384);
  SBAR(); LGKM0();
  __builtin_amdgcn_s_setprio(1);
  #pragma unroll
  for (int mf = 0; mf < 4; ++mf)
    #pragma unroll
    for (int nf = 0; nf < 4; ++nf) mma16<F16>(acc[mf][nf], af[mf], bfr[nf]);
  __builtin_amdgcn_s_setprio(0);
  SBAR();

  // ---- P2: A kk0 mf4-7 (reuse B); stage A(t+1) h1
  #pragma unroll
  for (int i = 0; i < 4; ++i) af[i] = *(const bf16x8*)(lA_k0 + BUF*32768 + (4+i)*2048);
  if (t + 1 < nkt) stg2(gA1 + 64, qA, dA + (BUF^1)*16384 + 8192);
  SBAR(); LGKM0();
  __builtin_amdgcn_s_setprio(1);
  #pragma unroll
  for (int mf = 0; mf < 4; ++mf)
    #pragma unroll
    for (int nf = 0; nf < 4; ++nf) mma16<F16>(acc[mf+4][nf], af[mf], bfr[nf]);
  __builtin_amdgcn_s_setprio(0);
  SBAR();

  // ---- P3: A kk1 mf0-3 + B kk1; stage B(t+2) h0 (half-tile granularity)
  #pragma unroll
  for (int i = 0; i < 4; ++i) af[i]  = *(const bf16x8*)(lA_k1 + BUF*32768 + i*2048);
  #pragma unroll
  for (int i = 0; i < 4; ++i) bfr[i] = *(const bf16x8*)(lB_k1 + BUF*32768 + i*2048);
  if (t + 2 < nkt) stg2(gB0 + 128, qB, dB + BUF*16384);
  SBAR(); LGKM0();
  __builtin_amdgcn_s_setprio(1);
  #pragma unroll
  for (int mf = 0; mf < 4; ++mf)
    #pragma unroll
    for (int nf = 0; nf < 4; ++nf) mma16<F16>(acc[mf][nf], af[mf], bfr[nf]);
  __builtin_amdgcn_s_setprio(0);
  SBAR();

  // ---- P4: A kk1 mf4-7; stage B(t+2) h1; counted vmcnt (leave B(t+2)'s 4 in flight)
  #pragma unroll
  for (int i = 0; i < 4; ++i) af[i] = *(const bf16x8*)(lA_k1 + BUF*32768 + (4+i)*2048);
  if (t + 2 < nkt){
    stg2(gB1 + 128, qB, dB + BUF*16384 + 8192);
    asm volatile("s_waitcnt vmcnt(4)" ::: "memory");   // tile t+1 landed; B(t+2) in flight
  } else if (t + 1 < nkt){
    asm volatile("s_waitcnt vmcnt(0)" ::: "memory");   // tail: drain A(t+1)
  }
  SBAR(); LGKM0();
  __builtin_amdgcn_s_setprio(1);
  #pragma unroll
  for (int mf = 0; mf < 4; ++mf)
    #pragma unroll
    for (int nf = 0; nf < 4; ++nf) mma16<F16>(acc[mf+4][nf], af[mf], bfr[nf]);
  __builtin_amdgcn_s_setprio(0);
  SBAR();

  gA0 += 64; gA1 += 64; gB0 += 64; gB1 += 64;          // advance to next K-tile
}

template<bool F16>
__device__ __forceinline__ void gemm256(const unsigned short* __restrict__ Ab, int lda,
                                        const unsigned short* __restrict__ Bb, int ldb,
                                        int nkt, unsigned short* sm, f32x4 (&acc)[8][4]){
  const int tid  = threadIdx.x;
  const int lane = tid & 63, l15 = lane & 15, lg = lane >> 4;
  const int wid  = tid >> 6;
  const int wrow0 = (wid >> 2) << 7;     // 0 / 128
  const int wcol0 = (wid & 3) << 6;      // 0 / 64 / 128 / 192

  const int srow = tid >> 3;                          // 0..63
  const int scol = ((tid & 7) ^ (srow & 7)) << 3;     // pre-swizzled chunk
  const unsigned short* gA0 = Ab + (size_t)srow*lda + scol;
  const unsigned short* gA1 = gA0 + (size_t)128*lda;
  const unsigned short* gB0 = Bb + (size_t)srow*ldb + scol;
  const unsigned short* gB1 = gB0 + (size_t)128*ldb;
  const size_t qA = (size_t)64*lda, qB = (size_t)64*ldb;
  unsigned short* dA = sm + tid*8;                    // linear LDS dests
  unsigned short* dB = sm + 32768 + tid*8;

  const int mswz = (l15 & 7) << 4;
  const char* smc = (const char*)sm;
  const char* lA_k0 = smc + ((wrow0 + l15) << 7) + (((lg << 4))      ^ mswz);
  const char* lA_k1 = smc + ((wrow0 + l15) << 7) + ((64 + (lg << 4)) ^ mswz);
  const char* lB_k0 = smc + 65536 + ((wcol0 + l15) << 7) + (((lg << 4))      ^ mswz);
  const char* lB_k1 = smc + 65536 + ((wcol0 + l15) << 7) + ((64 + (lg << 4)) ^ mswz);

  // prologue: A(0) h0+h1 -> Abuf0, B(0) -> Bbuf0, B(1) -> Bbuf1
  stg2(gA0, qA, dA);          stg2(gA1, qA, dA + 8192);
  stg2(gB0, qB, dB);          stg2(gB1, qB, dB + 8192);
  stg2(gB0 + 64, qB, dB + 16384);
  stg2(gB1 + 64, qB, dB + 16384 + 8192);
  asm volatile("s_waitcnt vmcnt(4)" ::: "memory");    // tile 0 fully landed
  SBAR();

  for (int t = 0; t < nkt; t += 2){
    ktile256<F16,0>(t,   nkt, gA0,gA1,gB0,gB1,qA,qB,dA,dB,lA_k0,lA_k1,lB_k0,lB_k1,acc);
    ktile256<F16,1>(t+1, nkt, gA0,gA1,gB0,gB1,qA,qB,dA,dB,lA_k0,lA_k1,lB_k0,lB_k1,acc);
  }
}

// ================= W transpose+convert (kept: tiny, scattered reads once) =================
__global__ __launch_bounds__(256) void k_cvt_wt(const float* __restrict__ Wq, const float* __restrict__ Wk,
                                                const float* __restrict__ Wv, unsigned short* __restrict__ Wt){
  int n = blockIdx.x*32 + threadIdx.x;
  int k = blockIdx.y*8  + threadIdx.y;
  float v;
  if (n < 128)      v = Wq[(size_t)k*128  + n];
  else if (n < 256) v = Wk[(size_t)k*128  + (n-128)];
  else              v = Wv[(size_t)k*1024 + (n-256)];
  Wt[(size_t)n*1024 + k] = f2h(v);
}

// ================= Q/K projection + fused convert — ROUND-12 PIPELINED =================
// Double-buffered LDS (64KB), ONE __syncthreads per kt. Per kt: issue x-loads(kt+1)
// -> regs and W-stage(kt+1) -> lsB^1 BEFORE MFMA(kt) (T14 issue-early); convert +
// ds_write lsA^1 AFTER MFMA(kt) (write-late). The per-kt syncthreads drain is now
// covered by MFMA+convert instead of exposed. All writes target buf^1 while reads
// hit buf (cross-buffer, race-free); barrier orders buf^1 reads after writes.
// Conversion values, MFMA order, write-sets identical to round 10 -> bit-identical.
__global__ __launch_bounds__(256) void k_projQK(const float* __restrict__ x,
                                                const unsigned short* __restrict__ Wt,
                                                const float* __restrict__ bq, const float* __restrict__ bk,
                                                unsigned short* __restrict__ Qh, unsigned short* __restrict__ Kh,
                                                unsigned short* __restrict__ xh){
  __shared__ unsigned short lsA[2][128*64], lsB[2][128*64];
  const int m0  = blockIdx.x * 128;
  const int sel = blockIdx.y;                // 0 = Q, 1 = K
  const int tid = threadIdx.x, lane = tid & 63;
  const int wr = ((tid >> 7) & 1) << 6;
  const int wc = ((tid >> 6) & 1) << 6;
  const int l15 = lane & 15, lg = lane >> 4;

  int rows_[4], kcs_[4];
  #pragma unroll
  for (int t = 0; t < 4; ++t){
    int idx = t*256 + tid;
    rows_[t] = idx >> 3;
    kcs_[t]  = ((idx & 7) ^ (rows_[t] & 7)) << 3;
  }
  const unsigned short* Wb = Wt + (size_t)sel*128*1024;

  float4 pre[4][2];
  auto issue = [&](int kt){
    #pragma unroll
    for (int t = 0; t < 4; ++t){
      const float* gx = x + (size_t)(m0 + rows_[t])*1024 + kt*64 + kcs_[t];
      pre[t][0] = *(const float4*)gx;
      pre[t][1] = *(const float4*)(gx + 4);
    }
  };
  auto writeA = [&](int kt, unsigned short* dstA){
    #pragma unroll
    for (int t = 0; t < 4; ++t){
      bf16x8 pk;
      pk[0] = (short)f2h(pre[t][0].x); pk[1] = (short)f2h(pre[t][0].y);
      pk[2] = (short)f2h(pre[t][0].z); pk[3] = (short)f2h(pre[t][0].w);
      pk[4] = (short)f2h(pre[t][1].x); pk[5] = (short)f2h(pre[t][1].y);
      pk[6] = (short)f2h(pre[t][1].z); pk[7] = (short)f2h(pre[t][1].w);
      *(bf16x8*)(dstA + (t*256 + tid)*8) = pk;
      if (sel == 0) *(bf16x8*)(xh + (size_t)(m0 + rows_[t])*1024 + kt*64 + kcs_[t]) = pk;
    }
  };

  f32x4 acc[4][4]; ZERO_ACC4(acc);

  // prologue: kt=0 into buf0 (latency exposed once)
  issue(0);
  stage_tile(Wb, 1024, lsB[0], tid);
  writeA(0, lsA[0]);
  __syncthreads();

  for (int kt = 0; kt < 16; ++kt){
    const int cur = kt & 1;
    if (kt + 1 < 16){
      issue(kt + 1);                                          // x(kt+1) -> regs
      stage_tile(Wb + (size_t)(kt+1)*64, 1024, lsB[cur^1], tid);  // W(kt+1) -> lsB^1
    }
    const unsigned short* At = lsA[cur];
    const unsigned short* Bt = lsB[cur];
    #pragma unroll
    for (int kk = 0; kk < 2; ++kk){
      bf16x8 af[4], bfr[4];
      #pragma unroll
      for (int mf = 0; mf < 4; ++mf) af[mf]  = frag_ld(At, wr + mf*16 + l15, kk*32 + lg*8);
      #pragma unroll
      for (int nf = 0; nf < 4; ++nf) bfr[nf] = frag_ld(Bt, wc + nf*16 + l15, kk*32 + lg*8);
      #pragma unroll
      for (int mf = 0; mf < 4; ++mf)
        #pragma unroll
        for (int nf = 0; nf < 4; ++nf)
          mma16<true>(acc[mf][nf], af[mf], bfr[nf]);
    }
    if (kt + 1 < 16) writeA(kt + 1, lsA[cur^1]);              // convert + ds_write (late)
    __syncthreads();
  }

  unsigned short* T  = sel ? Kh : Qh;
  const float* bias  = sel ? bk : bq;
  #pragma unroll
  for (int mf = 0; mf < 4; ++mf){
    #pragma unroll
    for (int nf = 0; nf < 4; ++nf){
      int c = wc + nf*16 + l15;
      float bi = bias[c];
      #pragma unroll
      for (int r = 0; r < 4; ++r){
        int gr = m0 + wr + mf*16 + lg*4 + r;
        T[(size_t)gr*128 + c] = f2h(acc[mf][nf][r] + bi);
      }
    }
  }
}

// ================= V projection: 256² core, grid 64M x 4N = 256 blocks (one pass) =================
__global__ __launch_bounds__(512, 2) void k_projV(const unsigned short* __restrict__ xh,
                                                  const unsigned short* __restrict__ Wt,
                                                  const float* __restrict__ bv,
                                                  unsigned short* __restrict__ Vt){
  extern __shared__ unsigned short sm[];
  const int bid = blockIdx.x;
  const int m0 = (bid & 63) << 8;            // 0..16128
  const int n0 = (bid >> 6) << 8;            // 0..768 (V column block)

  f32x4 acc[8][4]; ZERO_ACC8(acc);
  gemm256<true>(xh + (size_t)m0*1024, 1024,
                Wt + (size_t)(256 + n0)*1024, 1024, 16, sm, acc);

  const int tid = threadIdx.x, lane = tid & 63, l15 = lane & 15, lg = lane >> 4;
  const int wid = tid >> 6;
  const int wrow0 = (wid >> 2) << 7;
  const int wcol0 = (wid & 3) << 6;

  #pragma unroll
  for (int mf = 0; mf < 8; ++mf){
    int gr0 = m0 + wrow0 + mf*16 + lg*4;     // 4 consecutive seq rows
    int b = gr0 >> 11, t0 = gr0 & 2047;
    #pragma unroll
    for (int nf = 0; nf < 4; ++nf){
      int j = n0 + wcol0 + nf*16 + l15;      // 0..1023
      float bi = bv[j];
      ushort4 pk;
      pk.x = f2bf(acc[mf][nf][0] + bi);
      pk.y = f2bf(acc[mf][nf][1] + bi);
      pk.z = f2bf(acc[mf][nf][2] + bi);
      pk.w = f2bf(acc[mf][nf][3] + bi);
      *(ushort4*)(Vt + ((size_t)b*1024 + j)*2048 + t0) = pk;
    }
  }
}

// ================= scores: P = exp(QK^T) bf16 + row-sum atomics (r10 128² version) =================
__global__ __launch_bounds__(256) void k_scores(const unsigned short* __restrict__ Qh,
                                                const unsigned short* __restrict__ Kh,
                                                unsigned short* __restrict__ P, float* __restrict__ lsum){
  __shared__ unsigned short lsA[128*64], lsB[128*64];
  const int s0 = blockIdx.x * 128;
  const int t0 = blockIdx.y * 128;
  const int b  = blockIdx.z;
  f32x4 acc[4][4]; ZERO_ACC4(acc);
  gemm_core<true>(Qh + ((size_t)b*2048 + s0)*128, Kh + ((size_t)b*2048 + t0)*128, 128, 128, 2, lsA, lsB, acc);

  unsigned short* Pb = P + (size_t)b*2048*2048;
  float* lb = lsum + b*2048;
  const int tid = threadIdx.x, lane = tid & 63;
  const int wr = ((tid >> 7) & 1) << 6;
  const int wc = ((tid >> 6) & 1) << 6;
  const int l15 = lane & 15, lg = lane >> 4;

  #pragma unroll
  for (int mf = 0; mf < 4; ++mf){
    #pragma unroll
    for (int r = 0; r < 4; ++r){
      int sr = s0 + wr + mf*16 + lg*4 + r;
      float rsum = 0.f;
      #pragma unroll
      for (int nf = 0; nf < 4; ++nf){
        float e = __expf(acc[mf][nf][r]);
        unsigned short h = f2bf(e);
        int tc = t0 + wc + nf*16 + l15;
        Pb[(size_t)sr*2048 + tc] = h;
        rsum += bf2f(h);
      }
      #pragma unroll
      for (int d = 1; d < 16; d <<= 1) rsum += __shfl_xor(rsum, d);
      if (l15 == 0) atomicAdd(&lb[sr], rsum);
    }
  }
}

// ================= PV: 256² core, grid 256 (batch = bid&7 -> XCD) =================
__global__ __launch_bounds__(512, 2) void k_pv8(const unsigned short* __restrict__ P,
                                                const unsigned short* __restrict__ Vt,
                                                const float* __restrict__ lsum,
                                                float* __restrict__ out){
  extern __shared__ unsigned short sm[];
  const int bid = blockIdx.x;
  const int b   = bid & 7;
  const int r2  = bid >> 3;
  const int s0  = (r2 >> 2) << 8;
  const int j0  = (r2 & 3) << 8;

  f32x4 acc[8][4]; ZERO_ACC8(acc);
  gemm256<false>(P  + ((size_t)b*2048 + s0)*2048, 2048,
                 Vt + ((size_t)b*1024 + j0)*2048, 2048, 32, sm, acc);

  const int tid = threadIdx.x, lane = tid & 63, l15 = lane & 15, lg = lane >> 4;
  const int wid = tid >> 6;
  const int wrow0 = (wid >> 2) << 7;
  const int wcol0 = (wid & 3) << 6;

  const float* lb = lsum + b*2048;
  float* ob = out + (size_t)b*2048*1024;
  #pragma unroll
  for (int mf = 0; mf < 8; ++mf){
    #pragma unroll
    for (int r = 0; r < 4; ++r){
      int sr = s0 + wrow0 + mf*16 + lg*4 + r;
      float rl = 1.0f / lb[sr];
      #pragma unroll
      for (int nf = 0; nf < 4; ++nf){
        int jc = j0 + wcol0 + nf*16 + l15;
        float v = acc[mf][nf][r] * rl;
        ob[(size_t)sr*1024 + jc] = 1.0f - 2.0f/(1.0f + __expf(2.0f*v));
      }
    }
  }
}

extern "C" void kernel_launch(void* const* d_in, const int* in_sizes, int n_in,
                              void* d_out, int out_size, void* d_ws, size_t ws_size,
                              hipStream_t stream){
  const float* x  = (const float*)d_in[0];
  const float* Wq = (const float*)d_in[1];
  const float* bq = (const float*)d_in[2];
  const float* Wk = (const float*)d_in[3];
  const float* bk = (const float*)d_in[4];
  const float* Wv = (const float*)d_in[5];
  const float* bv = (const float*)d_in[6];
  float* out = (float*)d_out;

  char* ws = (char*)d_ws;
  const size_t MB = 1024*1024;
  unsigned short* Wt   = (unsigned short*)(ws);            // [1280][1024] fp16
  unsigned short* Qh   = (unsigned short*)(ws + 4*MB);     // [16384][128] fp16
  unsigned short* Kh   = (unsigned short*)(ws + 8*MB);
  unsigned short* Vt   = (unsigned short*)(ws + 12*MB);    // [8][1024][2048] bf16
  unsigned short* P    = (unsigned short*)(ws + 44*MB);    // [8][2048][2048] bf16
  float*          lsum = (float*)(ws + 108*MB);            // [8][2048] f32
  unsigned short* xh   = (unsigned short*)d_out;           // scratch: x fp16 in out buf (written by k_projQK sel0)

  hipMemsetAsync(lsum, 0, 16384*sizeof(float), stream);
  k_cvt_wt <<<dim3(40,128), dim3(32,8), 0, stream>>>(Wq, Wk, Wv, Wt);
  k_projQK <<<dim3(128,2), 256, 0, stream>>>(x, Wt, bq, bk, Qh, Kh, xh);
  k_projV  <<<256, 512, 131072, stream>>>(xh, Wt, bv, Vt);
  k_scores <<<dim3(16,16,8), 256, 0, stream>>>(Qh, Kh, P, lsum);
  k_pv8    <<<256, 512, 131072, stream>>>(P, Vt, lsum, out);
}